// Round 10
// baseline (293.560 us; speedup 1.0000x reference)
//
#include <hip/hip_runtime.h>

#define NN 512
#define DD 256

typedef float f32x4 __attribute__((ext_vector_type(4)));
typedef short s16x8 __attribute__((ext_vector_type(8)));

__device__ __forceinline__ unsigned short f2bf(float f) {
    unsigned u = __float_as_uint(f);
    u += 0x7fffu + ((u >> 16) & 1u);   // round-to-nearest-even
    return (unsigned short)(u >> 16);
}
__device__ __forceinline__ float bf2f(unsigned short s) {
    return __uint_as_float(((unsigned)s) << 16);
}
__device__ __forceinline__ unsigned packbf(float a, float b) {
    return ((unsigned)f2bf(b) << 16) | f2bf(a);
}

// ---------------------------------------------------------------------------
// K1: hb = h@W1.T + t_bias, hW2 = h@W2.T, hW4 = h@W4.T, w3b = bf16(W3),
//     zero the softmax accumulators (wacc, zacc).
// ---------------------------------------------------------------------------
__global__ __launch_bounds__(256) void k1_pre(
    const float* __restrict__ h,  const float* __restrict__ W1,
    const float* __restrict__ W2, const float* __restrict__ W4,
    const float* __restrict__ t_emb, const float* __restrict__ W_t,
    const float* __restrict__ W3,
    float* __restrict__ hb, float* __restrict__ hW2, float* __restrict__ hW4,
    unsigned short* __restrict__ w3b,
    float* __restrict__ wacc, float* __restrict__ zacc)
{
    __shared__ float xs[8][DD];
    __shared__ float st[DD];
    const int b = blockIdx.x;
    const int t = threadIdx.x;
    if (b < 64) {
        #pragma unroll
        for (int r = 0; r < 8; ++r) xs[r][t] = h[(size_t)(b * 8 + r) * DD + t];
        st[t] = t_emb[t];
        __syncthreads();
        float a1[8], a2[8], a4[8];
        #pragma unroll
        for (int r = 0; r < 8; ++r) { a1[r] = 0.f; a2[r] = 0.f; a4[r] = 0.f; }
        float tb = 0.f;
        for (int d = 0; d < DD; ++d) {
            const float w1 = W1[(size_t)t * DD + d];
            const float w2 = W2[(size_t)t * DD + d];
            const float w4 = W4[(size_t)t * DD + d];
            tb = fmaf(st[d], W_t[(size_t)t * DD + d], tb);
            #pragma unroll
            for (int r = 0; r < 8; ++r) {
                const float x = xs[r][d];
                a1[r] = fmaf(x, w1, a1[r]);
                a2[r] = fmaf(x, w2, a2[r]);
                a4[r] = fmaf(x, w4, a4[r]);
            }
        }
        #pragma unroll
        for (int r = 0; r < 8; ++r) {
            const size_t o = (size_t)(b * 8 + r) * DD + t;
            hb[o] = a1[r] + tb; hW2[o] = a2[r]; hW4[o] = a4[r];
        }
    } else if (b == 64) {
        for (int c = t; c < DD * DD / 4; c += 256) {
            const f32x4 v = *reinterpret_cast<const f32x4*>(W3 + (size_t)c * 4);
            *reinterpret_cast<uint2*>(w3b + (size_t)c * 4) =
                make_uint2(packbf(v[0], v[1]), packbf(v[2], v[3]));
        }
    } else {
        const f32x4 zero = (f32x4){0.f, 0.f, 0.f, 0.f};
        for (int c = t; c < NN * DD / 4; c += 256)
            *reinterpret_cast<f32x4*>(wacc + (size_t)c * 4) = zero;
        if (t < 256) { zacc[t] = 0.f; zacc[t + 256] = 0.f; }
    }
}

// ---------------------------------------------------------------------------
// K2 (transposed MFMA): D = mfma(A=w3b, B=e-tile) -> D[row=d, col=j].
// Lane owns 2 j-rows (col=l15, l15+16) x 16 d-values (d=w*64+m*16+lg*4+q)
// -> LN stats / normalize / gate / exp are LANE-LOCAL (in-lane adds + 2
// shfl + 1 small LDS round), replacing R4-R9's ~50-op shfl chains and two
// serial broadcast phases. e-tile staged bf16 XOR-swizzled (B-frag read =
// R9's verified A-frag read); w3b rows streamed from L2 with depth-4 reg
// prefetch (R8-verified). e_new staged bf16 in LDS (overlaying dead sA/sH2),
// drained coalesced; p[d] = per-thread conflict-free column pass; exp
// recomputed per-thread from b128 glog read (saves a barrier). 3 barriers.
// ---------------------------------------------------------------------------
__global__ __launch_bounds__(256) void k2_big(
    const float* __restrict__ e,
    const unsigned short* __restrict__ w3b,
    const float* __restrict__ hb, const float* __restrict__ hW2,
    const float* __restrict__ gate_w, const float* __restrict__ gate_b,
    const float* __restrict__ ln_e_w, const float* __restrict__ ln_e_b,
    float* __restrict__ out_e,
    float* __restrict__ wacc, float* __restrict__ zacc)
{
    const int b = blockIdx.x;
    const int row_base = b * 32;              // flat row = i*512 + j
    const int i = row_base >> 9;
    const int tid = threadIdx.x;
    const int w = tid >> 6;
    const int l = tid & 63;
    const int l15 = l & 15;
    const int lg = l >> 4;                    // 0..3

    // sBuf phase 1: sA = swizzled bf16 e-tile [0,16K); sH2 = swizzled bf16
    // hW2 slab [16K,32K). Phase 2 (after SB1): sOut = bf16 [32][264] e_new
    // staging tile overlaying both (16.5K).
    __shared__ __align__(16) unsigned char sBuf[32768];
    __shared__ __align__(16) float s_part[32][4][2];   // [j][wave][{s1,s2}]
    __shared__ __align__(16) float s_glog[32][4];      // [j][wave] gate partials
    __shared__ unsigned short s_hbu[DD];
    __shared__ float s_lnw[DD], s_lnb[DD], s_gw[DD];
    unsigned short* const sOut = (unsigned short*)sBuf;

    // ---- A-operand (w3b rows) depth-4 prefetch base ----
    const unsigned short* pA = w3b + (size_t)(w * 64 + l15) * DD + lg * 8;
    s16x8 bb[4][4];                           // [kk-slot][m]
    #pragma unroll
    for (int kk = 0; kk < 4; ++kk)
        #pragma unroll
        for (int m = 0; m < 4; ++m)
            bb[kk][m] = *reinterpret_cast<const s16x8*>(pA + (size_t)m * 16 * DD + kk * 32);

    // ---- stage e-tile -> swizzled bf16 sA ----
    {
        const float* esrc = e + (size_t)row_base * DD;
        f32x4 av[8];
        #pragma unroll
        for (int s = 0; s < 8; ++s)
            av[s] = *reinterpret_cast<const f32x4*>(esrc + (size_t)(s * 256 + tid) * 4);
        #pragma unroll
        for (int s = 0; s < 8; ++s) {
            const int flat = s * 256 + tid;
            const int r = flat >> 6;
            const int c4 = (flat & 63) * 4;
            const unsigned byte = ((unsigned)(r * 512 + c4 * 2)) ^ ((unsigned)(r & 7) << 4);
            *reinterpret_cast<uint2*>(sBuf + byte) =
                make_uint2(packbf(av[s][0], av[s][1]), packbf(av[s][2], av[s][3]));
        }
    }
    // ---- stage hW2 slab -> swizzled bf16 sH2 ----
    {
        const float* h2src = hW2 + (size_t)(row_base & 511) * DD;
        f32x4 hv[8];
        #pragma unroll
        for (int s = 0; s < 8; ++s)
            hv[s] = *reinterpret_cast<const f32x4*>(h2src + (size_t)(s * 256 + tid) * 4);
        #pragma unroll
        for (int s = 0; s < 8; ++s) {
            const int flat = s * 256 + tid;
            const int r = flat >> 6;
            const int c4 = (flat & 63) * 4;
            const unsigned byte = ((unsigned)(r * 512 + c4 * 2)) ^ ((unsigned)(r & 7) << 4);
            *reinterpret_cast<uint2*>(sBuf + 16384 + byte) =
                make_uint2(packbf(hv[s][0], hv[s][1]), packbf(hv[s][2], hv[s][3]));
        }
    }
    s_lnw[tid] = ln_e_w[tid];
    s_lnb[tid] = ln_e_b[tid];
    s_gw[tid]  = gate_w[tid];
    s_hbu[tid] = f2bf(hb[(size_t)i * DD + tid]);
    __syncthreads();                          // SB0

    // ---- MFMA K-loop: A = w3b regs (depth-4), B = e-frags from LDS ----
    f32x4 acc[4][2];
    #pragma unroll
    for (int m = 0; m < 4; ++m) { acc[m][0] = (f32x4){0,0,0,0}; acc[m][1] = (f32x4){0,0,0,0}; }

    const unsigned aswz = ((unsigned)(l15 & 7) << 4);
    #pragma unroll
    for (int kk = 0; kk < 8; ++kk) {
        s16x8 bfr[2];
        #pragma unroll
        for (int n = 0; n < 2; ++n) {
            const int j = n * 16 + l15;
            const unsigned byte = ((unsigned)(j * 512 + kk * 64 + lg * 16)) ^ aswz;
            bfr[n] = *reinterpret_cast<const s16x8*>(sBuf + byte);
        }
        #pragma unroll
        for (int m = 0; m < 4; ++m)
            #pragma unroll
            for (int n = 0; n < 2; ++n)
                acc[m][n] = __builtin_amdgcn_mfma_f32_16x16x32_bf16(bb[kk & 3][m], bfr[n], acc[m][n], 0, 0, 0);
        if (kk < 4) {
            #pragma unroll
            for (int m = 0; m < 4; ++m)
                bb[kk & 3][m] = *reinterpret_cast<const s16x8*>(pA + (size_t)m * 16 * DD + (kk + 4) * 32);
        }
    }

    // ---- bias + lane-local LN partial sums (d in-lane, j = lane col) ----
    const unsigned char* sH2 = sBuf + 16384;
    float s1[2] = {0.f, 0.f}, s2[2] = {0.f, 0.f};
    #pragma unroll
    for (int m = 0; m < 4; ++m) {
        const int d0 = w * 64 + m * 16 + lg * 4;
        const uint2 hbp = *reinterpret_cast<const uint2*>(&s_hbu[d0]);
        float hbv[4] = { bf2f((unsigned short)hbp.x), bf2f((unsigned short)(hbp.x >> 16)),
                         bf2f((unsigned short)hbp.y), bf2f((unsigned short)(hbp.y >> 16)) };
        #pragma unroll
        for (int n = 0; n < 2; ++n) {
            const int j = n * 16 + l15;
            const unsigned byte = ((unsigned)(j * 512 + d0 * 2)) ^ ((unsigned)(j & 7) << 4);
            const uint2 h2p = *reinterpret_cast<const uint2*>(sH2 + byte);
            const float h2v[4] = { bf2f((unsigned short)h2p.x), bf2f((unsigned short)(h2p.x >> 16)),
                                   bf2f((unsigned short)h2p.y), bf2f((unsigned short)(h2p.y >> 16)) };
            #pragma unroll
            for (int q = 0; q < 4; ++q) {
                const float v = acc[m][n][q] + hbv[q] + h2v[q];
                acc[m][n][q] = v;
                s1[n] += v;
                s2[n] = fmaf(v, v, s2[n]);
            }
        }
    }
    #pragma unroll
    for (int n = 0; n < 2; ++n) {
        s1[n] += __shfl_xor(s1[n], 16, 64); s1[n] += __shfl_xor(s1[n], 32, 64);
        s2[n] += __shfl_xor(s2[n], 16, 64); s2[n] += __shfl_xor(s2[n], 32, 64);
    }
    if (lg == 0) {
        #pragma unroll
        for (int n = 0; n < 2; ++n) {
            s_part[n * 16 + l15][w][0] = s1[n];
            s_part[n * 16 + l15][w][1] = s2[n];
        }
    }
    __syncthreads();                          // SB1 (sA/sH2 now dead)

    float mu[2], rs[2];
    #pragma unroll
    for (int n = 0; n < 2; ++n) {
        const int j = n * 16 + l15;
        float S1 = 0.f, S2 = 0.f;
        #pragma unroll
        for (int ww = 0; ww < 4; ++ww) { S1 += s_part[j][ww][0]; S2 += s_part[j][ww][1]; }
        const float m0 = S1 * (1.f / 256.f);
        mu[n] = m0;
        rs[n] = rsqrtf(S2 * (1.f / 256.f) - m0 * m0 + 1e-5f);
    }

    // ---- normalize, relu, gate partials, stage e_new (bf16) to sOut ----
    float gl[2] = {0.f, 0.f};
    #pragma unroll
    for (int m = 0; m < 4; ++m) {
        const int d0 = w * 64 + m * 16 + lg * 4;
        const f32x4 lw = *reinterpret_cast<const f32x4*>(&s_lnw[d0]);
        const f32x4 lb = *reinterpret_cast<const f32x4*>(&s_lnb[d0]);
        const f32x4 gw = *reinterpret_cast<const f32x4*>(&s_gw[d0]);
        #pragma unroll
        for (int n = 0; n < 2; ++n) {
            const int j = n * 16 + l15;
            float vv[4];
            #pragma unroll
            for (int q = 0; q < 4; ++q) {
                float v = (acc[m][n][q] - mu[n]) * rs[n] * lw[q] + lb[q];
                v = fmaxf(v, 0.f);
                vv[q] = v;
                gl[n] = fmaf(v, gw[q], gl[n]);
            }
            *reinterpret_cast<uint2*>(&sOut[j * 264 + d0]) =
                make_uint2(packbf(vv[0], vv[1]), packbf(vv[2], vv[3]));
        }
    }
    #pragma unroll
    for (int n = 0; n < 2; ++n) {
        gl[n] += __shfl_xor(gl[n], 16, 64);
        gl[n] += __shfl_xor(gl[n], 32, 64);
    }
    if (lg == 0) {
        s_glog[l15][w]      = gl[0];
        s_glog[l15 + 16][w] = gl[1];
    }
    __syncthreads();                          // SB2

    // ---- fused tail: p[d=tid] column pass + z (exp recomputed per thread) ----
    const float gb = gate_b[0];
    float pacc = 0.f, zsum = 0.f;
    #pragma unroll 4
    for (int r = 0; r < 32; ++r) {
        const f32x4 g4 = *reinterpret_cast<const f32x4*>(&s_glog[r][0]);
        const float ex = __expf((g4[0] + g4[1]) + (g4[2] + g4[3]) + gb);
        zsum += ex;
        pacc = fmaf(ex, bf2f(sOut[r * 264 + tid]), pacc);
    }
    atomicAdd(&wacc[(size_t)i * DD + tid], pacc);
    if (tid == 0) atomicAdd(&zacc[i], zsum);

    // ---- drain e_new: coalesced f32 stores (128B-line granularity) ----
    {
        const int rr = tid >> 3;              // row 0..31
        const int cb = (tid & 7) * 32;        // col base
        #pragma unroll
        for (int c = 0; c < 4; ++c) {
            const uint4 u = *reinterpret_cast<const uint4*>(&sOut[rr * 264 + cb + c * 8]);
            f32x4 o0, o1;
            o0[0] = bf2f((unsigned short)u.x); o0[1] = bf2f((unsigned short)(u.x >> 16));
            o0[2] = bf2f((unsigned short)u.y); o0[3] = bf2f((unsigned short)(u.y >> 16));
            o1[0] = bf2f((unsigned short)u.z); o1[1] = bf2f((unsigned short)(u.z >> 16));
            o1[2] = bf2f((unsigned short)u.w); o1[3] = bf2f((unsigned short)(u.w >> 16));
            float* dst = out_e + (size_t)(row_base + rr) * DD + cb + c * 8;
            *reinterpret_cast<f32x4*>(dst) = o0;
            *reinterpret_cast<f32x4*>(dst + 4) = o1;
        }
    }
}

// ---------------------------------------------------------------------------
// K4: h_new = h + relu(LN(hW4 + (wacc/z)@W5.T))
// ---------------------------------------------------------------------------
__global__ __launch_bounds__(256) void k4_final(
    const float* __restrict__ wacc, const float* __restrict__ zacc,
    const float* __restrict__ W5,
    const float* __restrict__ hW4, const float* __restrict__ h,
    const float* __restrict__ ln_h_w, const float* __restrict__ ln_h_b,
    float* __restrict__ out_h)
{
    const int i = blockIdx.x;
    const int k = threadIdx.x;
    __shared__ float xs[DD];
    __shared__ float red[256];

    const float zinv = 1.f / zacc[i];
    xs[k] = wacc[(size_t)i * DD + k] * zinv;
    __syncthreads();
    float a = 0.f;
    for (int d = 0; d < DD; ++d) a = fmaf(xs[d], W5[(size_t)k * DD + d], a);
    const float p = hW4[(size_t)i * DD + k] + a;

    red[k] = p;
    __syncthreads();
    for (int s = 128; s > 0; s >>= 1) {
        if (k < s) red[k] += red[k + s];
        __syncthreads();
    }
    const float mu = red[0] * (1.f / 256.f);
    __syncthreads();
    const float d0 = p - mu;
    red[k] = d0 * d0;
    __syncthreads();
    for (int s = 128; s > 0; s >>= 1) {
        if (k < s) red[k] += red[k + s];
        __syncthreads();
    }
    const float rs = rsqrtf(red[0] * (1.f / 256.f) + 1e-5f);
    float v = d0 * rs * ln_h_w[k] + ln_h_b[k];
    v = fmaxf(v, 0.f);
    out_h[(size_t)i * DD + k] = h[(size_t)i * DD + k] + v;
}

// ---------------------------------------------------------------------------
extern "C" void kernel_launch(void* const* d_in, const int* in_sizes, int n_in,
                              void* d_out, int out_size, void* d_ws, size_t ws_size,
                              hipStream_t stream)
{
    const float* h      = (const float*)d_in[0];
    const float* e      = (const float*)d_in[1];
    const float* t_emb  = (const float*)d_in[2];
    const float* W1     = (const float*)d_in[3];
    const float* W2     = (const float*)d_in[4];
    const float* W3     = (const float*)d_in[5];
    const float* W_t    = (const float*)d_in[6];
    const float* W4     = (const float*)d_in[7];
    const float* W5     = (const float*)d_in[8];
    const float* gate_w = (const float*)d_in[9];
    const float* gate_b = (const float*)d_in[10];
    const float* ln_e_w = (const float*)d_in[11];
    const float* ln_e_b = (const float*)d_in[12];
    const float* ln_h_w = (const float*)d_in[13];
    const float* ln_h_b = (const float*)d_in[14];

    float* out_h = (float*)d_out;
    float* out_e = out_h + NN * DD;

    // workspace layout (~2.3 MiB)
    float* wsf  = (float*)d_ws;
    float* hb   = wsf;                        // 131072 (hW1 + t_bias)
    float* hW2  = hb + NN * DD;               // 131072
    float* hW4  = hW2 + NN * DD;              // 131072
    float* wacc = hW4 + NN * DD;              // 131072
    float* zacc = wacc + NN * DD;             // 512
    unsigned short* w3b = (unsigned short*)(zacc + NN);  // 65536 ushort

    k1_pre<<<66, 256, 0, stream>>>(h, W1, W2, W4, t_emb, W_t, W3,
                                   hb, hW2, hW4, w3b, wacc, zacc);
    k2_big<<<8192, 256, 0, stream>>>(e, w3b, hb, hW2, gate_w, gate_b,
                                     ln_e_w, ln_e_b, out_e, wacc, zacc);
    k4_final<<<512, 256, 0, stream>>>(wacc, zacc, W5, hW4, h,
                                      ln_h_w, ln_h_b, out_h);
}